// Round 1
// 1190.952 us; speedup vs baseline: 1.2918x; 1.2918x over previous
//
#include <hip/hip_runtime.h>
#include <hip/hip_bf16.h>

#define TT 1024
#define BB 4
#define DD 256
#define VV 32000
#define NSWEEPS 26

typedef unsigned short u16;
typedef __attribute__((ext_vector_type(8))) short short8;   // 8 bf16 in 4 VGPRs
typedef __attribute__((ext_vector_type(4))) short short4v;
typedef __attribute__((ext_vector_type(4))) float f32x4;

static __device__ __forceinline__ short f2bf(float f) {
    union { float f; unsigned u; } v; v.f = f;
    unsigned u = v.u;
    unsigned r = (u + 0x7FFFu + ((u >> 16) & 1u)) >> 16;  // RNE
    return (short)r;
}

static __device__ __forceinline__ short8 load_f32x8_as_bf16(const float* p) {
    f32x4 a = *(const f32x4*)p;
    f32x4 b = *(const f32x4*)(p + 4);
    short8 r;
    r[0]=f2bf(a[0]); r[1]=f2bf(a[1]); r[2]=f2bf(a[2]); r[3]=f2bf(a[3]);
    r[4]=f2bf(b[0]); r[5]=f2bf(b[1]); r[6]=f2bf(b[2]); r[7]=f2bf(b[3]);
    return r;
}

// -------- head_w fp32 -> bf16 (plain [v][k] layout) --------
__global__ __launch_bounds__(256) void cvt_head_kernel(const float* __restrict__ hw,
                                                       u16* __restrict__ hb) {
    long i = ((long)blockIdx.x * 256 + threadIdx.x) * 4;   // VV*DD = 8,192,000 elems
    f32x4 v = *(const f32x4*)(hw + i);
    short4v o;
    o[0]=f2bf(v[0]); o[1]=f2bf(v[1]); o[2]=f2bf(v[2]); o[3]=f2bf(v[3]);
    *(short4v*)(hb + i) = o;
}

// -------- xp0[r=(t*4+b)][n] = embed[ids[b][t]] @ Wx0 + b0  (fp32 out) --------
__global__ __launch_bounds__(256) void xp0_kernel(const int* __restrict__ ids,
                                                  const float* __restrict__ embed,
                                                  const float* __restrict__ W0,
                                                  const float* __restrict__ b0,
                                                  float* __restrict__ xp0) {
    int tid = threadIdx.x;
    int l = tid & 63;
    int w = tid >> 6;            // wave -> N-slice of 64
    int mg = blockIdx.x;         // 0..255, 16 rows (4 timesteps)
    int t0 = mg * 4;
    int q = l >> 4;
    int nl = l & 15;
    int m = l & 15;              // A-row within tile
    int tA = t0 + (m >> 2);
    int bA = m & 3;
    int id = ids[bA * TT + tA];
    const float* xrow = embed + (long)id * DD;
    short8 afr[8];
#pragma unroll
    for (int kk = 0; kk < 8; ++kk)
        afr[kk] = load_f32x8_as_bf16(xrow + kk * 32 + q * 8);
    int N0 = w * 64;
    f32x4 acc[4];
#pragma unroll
    for (int nt = 0; nt < 4; ++nt) {
        int n = N0 + nt * 16 + nl;
        float bias = b0[n];
        acc[nt][0] = bias; acc[nt][1] = bias; acc[nt][2] = bias; acc[nt][3] = bias;
        const float* wrow = W0 + (long)n * 512;     // x-part: cols [0,256)
#pragma unroll
        for (int kk = 0; kk < 8; ++kk) {
            short8 bfr = load_f32x8_as_bf16(wrow + kk * 32 + q * 8);
            acc[nt] = __builtin_amdgcn_mfma_f32_16x16x32_bf16(afr[kk], bfr, acc[nt], 0, 0, 0);
        }
    }
#pragma unroll
    for (int nt = 0; nt < 4; ++nt) {
        int n = N0 + nt * 16 + nl;
#pragma unroll
        for (int reg = 0; reg < 4; ++reg)
            xp0[((long)(t0 + q) * BB + reg) * DD + n] = acc[nt][reg];   // row=4q+reg -> t=t0+q, b=reg
    }
}

// -------- one Jacobi sweep over all t --------
// h0^k_t = tanh(xp0_t + h0^{k-1}_{t-1} @ Wh0)
// h1^k_t = tanh(b1 + h0^{k-1}_t @ Wx1 + h1^{k-1}_{t-1} @ Wh1)
// h buffers: [slot=t+1][b][d] bf16, slot 0 = zeros.
__global__ __launch_bounds__(256) void sweep_kernel(const u16* __restrict__ sh0,
                                                    const u16* __restrict__ sh1,
                                                    u16* __restrict__ dh0,
                                                    u16* __restrict__ dh1,
                                                    const float* __restrict__ W0,
                                                    const float* __restrict__ W1,
                                                    const float* __restrict__ b1,
                                                    const float* __restrict__ xp0,
                                                    float* __restrict__ h0fin,
                                                    float* __restrict__ h1fin) {
    __shared__ short lds[3 * 16384];        // 96 KB: Wh0 | Wx1 | Wh1 slices, frag layout
    int tid = threadIdx.x;
    int bid = blockIdx.x;                   // 256 blocks = 64 M-groups x 4 N-slices
    int mg = bid >> 2;
    int ns = bid & 3;
    int N0 = ns * 64;
    // stage weight slices (fp32 -> bf16, MFMA-B fragment order)
    for (int task = tid; task < 6144; task += 256) {
        int mat = task >> 11;               // 0..2
        int rem = task & 2047;              // (nt*8+kk)*64 + lane
        int ll = rem & 63;
        int ntkk = rem >> 6;
        int nt = ntkk >> 3, kk = ntkk & 7;
        int n = N0 + nt * 16 + (ll & 15);
        int kbase = kk * 32 + (ll >> 4) * 8;
        const float* src;
        if (mat == 0)      src = W0 + (long)n * 512 + 256 + kbase;   // Wh0
        else if (mat == 1) src = W1 + (long)n * 512 + kbase;         // Wx1
        else               src = W1 + (long)n * 512 + 256 + kbase;   // Wh1
        short8 v = load_f32x8_as_bf16(src);
        *(short8*)&lds[task * 8] = v;
    }
    __syncthreads();

    int l = tid & 63;
    int w = tid >> 6;
    int t0 = mg * 16 + w * 4;               // 4 timesteps per wave
    int q = l >> 4;
    int nl = l & 15;
    int m = l & 15;
    int trow = t0 + (m >> 2);
    int bA = m & 3;
    long baseS = (long)trow * (BB * DD) + bA * DD;           // shifted read: slot t  -> h_{t-1}
    long baseU = (long)(trow + 1) * (BB * DD) + bA * DD;     // unshifted:   slot t+1 -> h_t
    short8 a0[8], a1x[8], a1h[8];
#pragma unroll
    for (int kk = 0; kk < 8; ++kk) {
        int ko = kk * 32 + q * 8;
        a0[kk]  = *(const short8*)(sh0 + baseS + ko);
        a1x[kk] = *(const short8*)(sh0 + baseU + ko);
        a1h[kk] = *(const short8*)(sh1 + baseS + ko);
    }
    int t = t0 + q;                         // C-layout: row=4q+reg -> t=t0+q, b=reg
    // ---- layer 0 ----
    f32x4 acc[4];
#pragma unroll
    for (int nt = 0; nt < 4; ++nt) {
        int n = N0 + nt * 16 + nl;
#pragma unroll
        for (int reg = 0; reg < 4; ++reg)
            acc[nt][reg] = xp0[((long)t * BB + reg) * DD + n];
#pragma unroll
        for (int kk = 0; kk < 8; ++kk) {
            short8 bf = *(short8*)&lds[((0 * 2048) + (nt * 8 + kk) * 64 + l) * 8];
            acc[nt] = __builtin_amdgcn_mfma_f32_16x16x32_bf16(a0[kk], bf, acc[nt], 0, 0, 0);
        }
    }
#pragma unroll
    for (int nt = 0; nt < 4; ++nt) {
        int n = N0 + nt * 16 + nl;
#pragma unroll
        for (int reg = 0; reg < 4; ++reg) {
            float v = tanhf(acc[nt][reg]);
            dh0[(long)(t + 1) * (BB * DD) + reg * DD + n] = (u16)f2bf(v);
            if (t == TT - 1) h0fin[reg * DD + n] = v;
        }
    }
    // ---- layer 1 ----
#pragma unroll
    for (int nt = 0; nt < 4; ++nt) {
        int n = N0 + nt * 16 + nl;
        float bias = b1[n];
        acc[nt][0] = bias; acc[nt][1] = bias; acc[nt][2] = bias; acc[nt][3] = bias;
#pragma unroll
        for (int kk = 0; kk < 8; ++kk) {
            short8 bf = *(short8*)&lds[((1 * 2048) + (nt * 8 + kk) * 64 + l) * 8];
            acc[nt] = __builtin_amdgcn_mfma_f32_16x16x32_bf16(a1x[kk], bf, acc[nt], 0, 0, 0);
        }
#pragma unroll
        for (int kk = 0; kk < 8; ++kk) {
            short8 bf = *(short8*)&lds[((2 * 2048) + (nt * 8 + kk) * 64 + l) * 8];
            acc[nt] = __builtin_amdgcn_mfma_f32_16x16x32_bf16(a1h[kk], bf, acc[nt], 0, 0, 0);
        }
    }
#pragma unroll
    for (int nt = 0; nt < 4; ++nt) {
        int n = N0 + nt * 16 + nl;
#pragma unroll
        for (int reg = 0; reg < 4; ++reg) {
            float v = tanhf(acc[nt][reg]);
            dh1[(long)(t + 1) * (BB * DD) + reg * DD + n] = (u16)f2bf(v);
            if (t == TT - 1) h1fin[reg * DD + n] = v;
        }
    }
}

// -------- logits = h1 @ head_w^T  (M=4096, N=32000, K=256) --------
// v2: (a) XCD-chunked bid swizzle: 16 consecutive per-XCD work-ids share one hb
//     N-slice -> hb L2-resident per XCD (fetch ~16 MB instead of ~260 MB).
//     (b) nontemporal stores for out: write-once stream must not allocate in L2
//     (kills RFO fetch + stops evicting hb/h1).
//     (c) store each nt tile right after its MFMAs: acc live range = 8 regs
//     instead of 128 -> higher occupancy, smooth store stream.
__global__ __launch_bounds__(512, 3) void head_kernel(const u16* __restrict__ h1,
                                                      const u16* __restrict__ hb,
                                                      float* __restrict__ out) {
    int tid = threadIdx.x;
    int l = tid & 63;
    int w = tid >> 6;            // 8 waves
    int bid = blockIdx.x;        // 2000 blocks; dispatch round-robins bid over 8 XCDs
    int xcd = bid & 7;
    int wid = xcd * 250 + (bid >> 3);   // contiguous 250-chunk per XCD, bijective
    int nb = wid >> 4;           // 0..124: 16 consecutive wids (same XCD) share nb
    int mgp = wid & 15;          // 0..15
    int Mbase = mgp * 256 + w * 32;
    int N0 = nb * 256;
    int q = l >> 4;
    int nl = l & 15;
    int m = l & 15;
    short8 afr[2][8];
#pragma unroll
    for (int ag = 0; ag < 2; ++ag) {
        int r = Mbase + ag * 16 + m;
        int tt = r >> 2, b = r & 3;
        long base = (long)(tt + 1) * (BB * DD) + b * DD;     // h1 final, slot t+1
#pragma unroll
        for (int kk = 0; kk < 8; ++kk)
            afr[ag][kk] = *(const short8*)(h1 + base + kk * 32 + q * 8);
    }
#pragma unroll 1
    for (int nt = 0; nt < 16; ++nt) {
        long brow = (long)(N0 + nt * 16 + nl) * DD;
        f32x4 acc0 = {0.f, 0.f, 0.f, 0.f};
        f32x4 acc1 = {0.f, 0.f, 0.f, 0.f};
#pragma unroll
        for (int kk = 0; kk < 8; ++kk) {
            short8 bfr = *(const short8*)(hb + brow + kk * 32 + q * 8);
            acc0 = __builtin_amdgcn_mfma_f32_16x16x32_bf16(afr[0][kk], bfr, acc0, 0, 0, 0);
            acc1 = __builtin_amdgcn_mfma_f32_16x16x32_bf16(afr[1][kk], bfr, acc1, 0, 0, 0);
        }
        int col = N0 + nt * 16 + nl;
#pragma unroll
        for (int reg = 0; reg < 4; ++reg) {
            int r0 = Mbase + q * 4 + reg;            // ag=0 row
            __builtin_nontemporal_store(acc0[reg],
                &out[((long)((r0 & 3) * TT + (r0 >> 2))) * VV + col]);
            int r1 = r0 + 16;                        // ag=1 row
            __builtin_nontemporal_store(acc1[reg],
                &out[((long)((r1 & 3) * TT + (r1 >> 2))) * VV + col]);
        }
    }
}

__global__ __launch_bounds__(256) void finals_kernel(const float* __restrict__ h0f,
                                                     const float* __restrict__ h1f,
                                                     float* __restrict__ out) {
    int i = blockIdx.x * 256 + threadIdx.x;   // 2048
    out[(long)BB * TT * VV + i] = (i < 1024) ? h0f[i] : h1f[i - 1024];
}

extern "C" void kernel_launch(void* const* d_in, const int* in_sizes, int n_in,
                              void* d_out, int out_size, void* d_ws, size_t ws_size,
                              hipStream_t stream) {
    const int* ids = (const int*)d_in[0];
    const float* embed = (const float*)d_in[1];
    const float* W0 = (const float*)d_in[2];
    const float* b0 = (const float*)d_in[3];
    const float* W1 = (const float*)d_in[4];
    const float* b1 = (const float*)d_in[5];
    const float* head_w = (const float*)d_in[6];
    float* out = (float*)d_out;

    char* ws = (char*)d_ws;
    size_t off = 0;
    auto alloc = [&](size_t bytes) -> void* {
        void* p = ws + off;
        off += (bytes + 255) & ~(size_t)255;
        return p;
    };
    const size_t HB_BYTES = (size_t)(TT + 1) * BB * DD * 2;      // 2,099,200
    float* xp0 = (float*)alloc((size_t)TT * BB * DD * 4);
    u16* h0A = (u16*)alloc(HB_BYTES);
    u16* h0B = (u16*)alloc(HB_BYTES);
    u16* h1A = (u16*)alloc(HB_BYTES);
    u16* h1B = (u16*)alloc(HB_BYTES);
    u16* hb  = (u16*)alloc((size_t)VV * DD * 2);
    float* h0f = (float*)alloc(BB * DD * 4);
    float* h1f = (float*)alloc(BB * DD * 4);

    // h^0 = 0 (full zero of A buffers); zero row (slot 0) of B buffers
    hipMemsetAsync(h0A, 0, HB_BYTES, stream);
    hipMemsetAsync(h1A, 0, HB_BYTES, stream);
    hipMemsetAsync(h0B, 0, (size_t)BB * DD * 2, stream);
    hipMemsetAsync(h1B, 0, (size_t)BB * DD * 2, stream);

    cvt_head_kernel<<<8000, 256, 0, stream>>>(head_w, hb);
    xp0_kernel<<<256, 256, 0, stream>>>(ids, embed, W0, b0, xp0);

    const u16* s0 = h0A; const u16* s1 = h1A;
    u16* d0 = h0B; u16* d1 = h1B;
    for (int s = 0; s < NSWEEPS; ++s) {
        sweep_kernel<<<256, 256, 0, stream>>>(s0, s1, d0, d1, W0, W1, b1, xp0, h0f, h1f);
        const u16* t0p = s0; s0 = d0; d0 = (u16*)t0p;
        const u16* t1p = s1; s1 = d1; d1 = (u16*)t1p;
    }
    head_kernel<<<2000, 512, 0, stream>>>(s1, hb, out);
    finals_kernel<<<8, 256, 0, stream>>>(h0f, h1f, out);
}